// Round 6
// baseline (166.513 us; speedup 1.0000x reference)
//
#include <hip/hip_runtime.h>
#include <hip/hip_bf16.h>

// B=8, S=128, E=50, D=300, DE=50 — ALL I/O FLOAT32.
// out: node[307200] | edge[6553600].  ws (floats): R1[51200] | R2[51200]
// XW (=x@Ww) parked in the edge region of d_out; overwritten by k_edge.

typedef __bf16 bf16x8 __attribute__((ext_vector_type(8)));
typedef float f32x4 __attribute__((ext_vector_type(4)));

__device__ __forceinline__ unsigned short f2bf(float f) {
    __hip_bfloat16 h = __float2bfloat16(f);
    union { __hip_bfloat16 h; unsigned short u; } c; c.h = h; return c.u;
}

// ---------------- K0: XW[row,d] = sum_k x[row,k] * Ww[k,d] ---------------------
__global__ void __launch_bounds__(320) k_xw(
    const float* __restrict__ x, const float* __restrict__ Ww,
    float* __restrict__ XW)
{
    __shared__ __align__(16) float xr[304];
    int tid = threadIdx.x;
    int row = blockIdx.x;                       // b*128 + j
    if (tid < 300) xr[tid] = x[(size_t)row * 300 + tid];
    else if (tid < 304) xr[tid] = 0.f;
    __syncthreads();
    if (tid < 300) {
        const float* wp = Ww + tid;
        const f32x4* x4 = (const f32x4*)xr;
        float acc = 0.f;
#pragma unroll 5
        for (int k4 = 0; k4 < 75; ++k4) {
            f32x4 xv = x4[k4];
            int k = k4 * 4;
            acc += xv[0] * wp[(k + 0) * 300];
            acc += xv[1] * wp[(k + 1) * 300];
            acc += xv[2] * wp[(k + 2) * 300];
            acc += xv[3] * wp[(k + 3) * 300];
        }
        XW[(size_t)row * 300 + tid] = acc;
    }
}

// ---------------- K1: per-row msum + h=M@XW+Wb + LN + relu + R1/R2 -------------
// one block per row (b*128+i); 256 threads; 4 blocks/CU.
__global__ void __launch_bounds__(256) k_node(
    const float* __restrict__ wps,
    const float* __restrict__ wa,
    const float* __restrict__ XW,
    const float* __restrict__ Wb,
    const float* __restrict__ lna,
    const float* __restrict__ lnb,
    const float* __restrict__ Rw,
    const float* __restrict__ rb,
    float* __restrict__ node_out,
    float* __restrict__ R1, float* __restrict__ R2)
{
    __shared__ __align__(16) float stage[6400];   // wps row
    __shared__ float Ml[128];
    __shared__ float srcL[352];                   // [diag(50) | node(300)] (+pad)
    __shared__ float p1s[5][50], p2s[5][50];
    __shared__ float red[8];
    __shared__ float stats[2];
    int tid = threadIdx.x;
    int row = blockIdx.x;                  // b*128 + i
    int b = row >> 7, i = row & 127;

    // ---- phase A: stage wps row (coalesced) + diag(wa) ----
    const float4* w4 = (const float4*)(wps + (size_t)row * 6400);
    float4* s4 = (float4*)stage;
    for (int t = tid; t < 1600; t += 256) s4[t] = w4[t];
    if (tid < 50) srcL[tid] = wa[((size_t)row * 128 + i) * 50 + tid];
    if (tid >= 350 - 256 && tid < 96) {}   // (no-op, keeps srcL tail uninit-free below)
    __syncthreads();

    // ---- M[j] = mean_e + self-loop ----
    if (tid < 128) {
        const float* p = stage + tid * 50;
        float s = 0.f;
#pragma unroll
        for (int e = 0; e < 50; ++e) s += p[e];
        Ml[tid] = s * (1.0f / 50.0f) + ((tid == i) ? 1.0f : 0.0f);
    }
    __syncthreads();

    // ---- h[d] = Wb[d] + sum_j Ml[j] * XW[b,j,d]  (d0=tid, d1=256+tid clamped) ----
    int d0 = tid;
    bool has2 = (tid < 44);
    int d1 = has2 ? 256 + tid : 299;
    float h0 = Wb[d0];
    float h1 = Wb[d1];
    {
        const float* xp = XW + (size_t)b * 38400;
#pragma unroll 16
        for (int j = 0; j < 128; ++j) {
            float m = Ml[j];
            h0 += m * xp[j * 300 + d0];
            h1 += m * xp[j * 300 + d1];
        }
    }

    // ---- LN stats over 300 (register reduce) ----
    {
        float s1 = h0 + (has2 ? h1 : 0.f);
        float s2 = h0 * h0 + (has2 ? h1 * h1 : 0.f);
        for (int off = 32; off > 0; off >>= 1) {
            s1 += __shfl_down(s1, off);
            s2 += __shfl_down(s2, off);
        }
        int wv = tid >> 6, lane = tid & 63;
        if (lane == 0) { red[wv] = s1; red[4 + wv] = s2; }
    }
    __syncthreads();
    if (tid == 0) {
        float s1 = red[0] + red[1] + red[2] + red[3];
        float s2 = red[4] + red[5] + red[6] + red[7];
        float mean = s1 * (1.0f / 300.0f);
        float var = (s2 - 300.0f * mean * mean) * (1.0f / 299.0f);
        var = fmaxf(var, 0.0f);
        stats[0] = mean;
        stats[1] = 1.0f / (sqrtf(var) + 1e-6f);
    }
    __syncthreads();

    // ---- node = relu(LN(h)) -> global + srcL ----
    {
        float mean = stats[0], inv = stats[1];
        float n0 = fmaxf(lna[d0] * (h0 - mean) * inv + lnb[d0], 0.f);
        node_out[(size_t)row * 300 + d0] = n0;
        srcL[50 + d0] = n0;
        if (has2) {
            float n1 = fmaxf(lna[d1] * (h1 - mean) * inv + lnb[d1], 0.f);
            node_out[(size_t)row * 300 + d1] = n1;
            srcL[50 + d1] = n1;
        }
    }
    __syncthreads();

    // ---- R1/R2: split-K x5 over src=[diag|node] ----
    if (tid < 250) {
        int p = tid / 50, k = tid % 50;
        int srcOff, w1b, w2b, len;
        if (p == 0) { srcOff = 0;  w1b = 50 * 50;  w2b = 100 * 50; len = 50; }
        else {
            int dd = (p - 1) * 75;
            srcOff = 50 + dd; w1b = (150 + dd) * 50; w2b = (450 + dd) * 50; len = 75;
        }
        float r1 = 0.f, r2 = 0.f;
        const float* w1p = Rw + w1b + k;
        const float* w2p = Rw + w2b + k;
#pragma unroll 5
        for (int t = 0; t < len; ++t) {
            float sv = srcL[srcOff + t];
            r1 += sv * w1p[t * 50];
            r2 += sv * w2p[t * 50];
        }
        p1s[p][k] = r1; p2s[p][k] = r2;
    }
    __syncthreads();
    if (tid < 50) {
        float s1 = 0.f, s2 = rb[tid];
#pragma unroll
        for (int p = 0; p < 5; ++p) { s1 += p1s[p][tid]; s2 += p2s[p][tid]; }
        R1[(size_t)row * 50 + tid] = s1;
        R2[(size_t)row * 50 + tid] = s2;
    }
}

// ---------------- K2: edge_out = wa·Rw[0:50] (MFMA) + R1[j] + R2[i] ------------
__global__ void __launch_bounds__(256) k_edge(
    const float* __restrict__ wa,
    const float* __restrict__ Rw,
    const float* __restrict__ R1, const float* __restrict__ R2,
    float* __restrict__ eout)
{
    __shared__ __align__(16) unsigned char smem[27648];
    unsigned short* waA  = (unsigned short*)smem;            // 128*72 bf16
    unsigned short* rwBT = (unsigned short*)(smem + 18432);  // 64*72 bf16
    float* outF = (float*)smem;                              // alias: 6400 floats
    int tid = threadIdx.x;
    int bi = blockIdx.x;       // b*128 + i
    int b = bi >> 7;

    for (int idx = tid; idx < 2304; idx += 256) ((unsigned int*)rwBT)[idx] = 0u;
    for (int idx = tid; idx < 1408; idx += 256) {            // zero waA pad e in [50,72)
        int j = idx / 11, c = idx % 11;
        *((unsigned int*)(waA + j * 72 + 50) + c) = 0u;
    }
    __syncthreads();

    const float2* wap = (const float2*)(wa + (size_t)bi * 6400);
    for (int idx = tid; idx < 3200; idx += 256) {
        float2 v = wap[idx];
        int f = idx * 2;
        int j = f / 50, e = f % 50;
        unsigned int pack = (unsigned int)f2bf(v.x) | ((unsigned int)f2bf(v.y) << 16);
        *(unsigned int*)(waA + j * 72 + e) = pack;
    }
    for (int idx = tid; idx < 2500; idx += 256) {            // transpose+cvt Rw[0:50][0:50]
        int e = idx / 50, kk = idx % 50;
        rwBT[kk * 72 + e] = f2bf(Rw[idx]);
    }
    __syncthreads();

    int lane = tid & 63, wv = tid >> 6;
    int q = lane >> 4, lr = lane & 15;
    f32x4 acc[2][4] = {};

#pragma unroll
    for (int ks = 0; ks < 2; ++ks) {
        int e0 = ks * 32 + q * 8;
        bf16x8 a0 = *(const bf16x8*)&waA[(wv * 32 + lr) * 72 + e0];
        bf16x8 a1 = *(const bf16x8*)&waA[(wv * 32 + 16 + lr) * 72 + e0];
#pragma unroll
        for (int nt = 0; nt < 4; ++nt) {
            bf16x8 bb = *(const bf16x8*)&rwBT[(nt * 16 + lr) * 72 + e0];
            acc[0][nt] = __builtin_amdgcn_mfma_f32_16x16x32_bf16(a0, bb, acc[0][nt], 0, 0, 0);
            acc[1][nt] = __builtin_amdgcn_mfma_f32_16x16x32_bf16(a1, bb, acc[1][nt], 0, 0, 0);
        }
    }
    __syncthreads();   // staging LDS dead; alias as outF

    const float* r2p = R2 + (size_t)bi * 50;
#pragma unroll
    for (int nt = 0; nt < 4; ++nt) {
        int kk = nt * 16 + lr;
        if (kk < 50) {
            float r2v = r2p[kk];
#pragma unroll
            for (int mi = 0; mi < 2; ++mi) {
                int jbase = wv * 32 + mi * 16 + q * 4;
#pragma unroll
                for (int r = 0; r < 4; ++r)
                    outF[(jbase + r) * 50 + kk] = acc[mi][nt][r] + r2v;
            }
        }
    }
    __syncthreads();

    const float4* R1b = (const float4*)(R1 + (size_t)b * 6400);
    const float4* L4  = (const float4*)outF;
    float4* op4 = (float4*)(eout + (size_t)bi * 6400);
    for (int f4 = tid; f4 < 1600; f4 += 256) {
        float4 v = L4[f4];
        float4 r = R1b[f4];
        v.x += r.x; v.y += r.y; v.z += r.z; v.w += r.w;
        op4[f4] = v;
    }
}

extern "C" void kernel_launch(void* const* d_in, const int* in_sizes, int n_in,
                              void* d_out, int out_size, void* d_ws, size_t ws_size,
                              hipStream_t stream)
{
    const float* wps = (const float*)d_in[0];
    const float* wa  = (const float*)d_in[1];
    const float* x   = (const float*)d_in[2];
    // d_in[3] self_loop: identity on every channel, folded into msum (+1 on diag)
    const float* Ww  = (const float*)d_in[4];
    const float* Wb  = (const float*)d_in[5];
    const float* lna = (const float*)d_in[6];
    const float* lnb = (const float*)d_in[7];
    const float* Rw  = (const float*)d_in[8];
    const float* rb  = (const float*)d_in[9];

    float* R1 = (float*)d_ws;            // 51200 floats
    float* R2 = ((float*)d_ws) + 51200;  // 51200 floats

    float* node_out = (float*)d_out;             // 307200 floats
    float* edge_out = node_out + 307200;         // 6553600 floats
    float* XW = edge_out;                        // scratch; overwritten by k_edge

    k_xw  <<<1024, 320, 0, stream>>>(x, Ww, XW);
    k_node<<<1024, 256, 0, stream>>>(wps, wa, XW, Wb, lna, lnb, Rw, rb,
                                     node_out, R1, R2);
    k_edge<<<1024, 256, 0, stream>>>(wa, Rw, R1, R2, edge_out);
}

// Round 7
// 165.219 us; speedup vs baseline: 1.0078x; 1.0078x over previous
//
#include <hip/hip_runtime.h>
#include <hip/hip_bf16.h>

// B=8, S=128, E=50, D=300, DE=50 — ALL I/O FLOAT32.
// out: node[307200] | edge[6553600].  ws (floats): R1[51200] | R2[51200]

typedef __bf16 bf16x8 __attribute__((ext_vector_type(8)));
typedef float f32x4 __attribute__((ext_vector_type(4)));

__device__ __forceinline__ unsigned short f2bf(float f) {
    __hip_bfloat16 h = __float2bfloat16(f);
    union { __hip_bfloat16 h; unsigned short u; } c; c.h = h; return c.u;
}

// ---------------- K1: per-row  M=mean_e(wps)+I ; Axm=M@x ; h=Axm@Ww+Wb ;
// ----------------      LN(unbiased std+eps) ; relu ; R1/R2 refine parts.
// one block per row (b*128+i); 256 threads; ~4 blocks/CU.
__global__ void __launch_bounds__(256) k_node(
    const float* __restrict__ wps,
    const float* __restrict__ wa,
    const float* __restrict__ x,
    const float* __restrict__ Ww,
    const float* __restrict__ Wb,
    const float* __restrict__ lna,
    const float* __restrict__ lnb,
    const float* __restrict__ Rw,
    const float* __restrict__ rb,
    float* __restrict__ node_out,
    float* __restrict__ R1, float* __restrict__ R2)
{
    __shared__ __align__(16) float stage[6400];   // wps row (25.6 KB)
    __shared__ float Ml[128];
    __shared__ float axm[304];
    __shared__ float srcL[352];                   // [diag(50) | node(300)]
    __shared__ float p1s[5][50], p2s[5][50];
    __shared__ float red[8];
    __shared__ float stats[2];
    int tid = threadIdx.x;
    int row = blockIdx.x;                  // b*128 + i
    int b = row >> 7, i = row & 127;

    // ---- stage wps row (coalesced) + diag(wa) ----
    const float4* w4 = (const float4*)(wps + (size_t)row * 6400);
    float4* s4 = (float4*)stage;
    for (int t = tid; t < 1600; t += 256) s4[t] = w4[t];
    if (tid < 50) srcL[tid] = wa[((size_t)row * 128 + i) * 50 + tid];
    __syncthreads();

    // ---- M[j] = mean_e + self-loop ----
    if (tid < 128) {
        const float* p = stage + tid * 50;
        float s = 0.f;
#pragma unroll
        for (int e = 0; e < 50; ++e) s += p[e];
        Ml[tid] = s * (1.0f / 50.0f) + ((tid == i) ? 1.0f : 0.0f);
    }
    __syncthreads();

    // ---- Axm[d] = sum_j Ml[j] * x[b,j,d]   (x[b] is L2-resident, 150 KB) ----
    int d0 = tid;
    bool has2 = (tid < 44);
    int d1 = has2 ? 256 + tid : 299;
    {
        float a0 = 0.f, a1 = 0.f;
        const float* xp = x + (size_t)b * 38400;
#pragma unroll 16
        for (int j = 0; j < 128; ++j) {
            float m = Ml[j];
            a0 += m * xp[j * 300 + d0];
            a1 += m * xp[j * 300 + d1];
        }
        axm[d0] = a0;
        if (has2) axm[d1] = a1;
    }
    __syncthreads();

    // ---- h[d] = Wb[d] + sum_k axm[k] * Ww[k,d]   (Ww L2-resident, 360 KB) ----
    float h0 = Wb[d0];
    float h1 = Wb[d1];
    {
        const float* wp0 = Ww + d0;
        const float* wp1 = Ww + d1;
        const f32x4* a4 = (const f32x4*)axm;
#pragma unroll 5
        for (int k4 = 0; k4 < 75; ++k4) {
            f32x4 av = a4[k4];
            int k = k4 * 4;
            h0 += av[0] * wp0[(k + 0) * 300];
            h0 += av[1] * wp0[(k + 1) * 300];
            h0 += av[2] * wp0[(k + 2) * 300];
            h0 += av[3] * wp0[(k + 3) * 300];
            h1 += av[0] * wp1[(k + 0) * 300];
            h1 += av[1] * wp1[(k + 1) * 300];
            h1 += av[2] * wp1[(k + 2) * 300];
            h1 += av[3] * wp1[(k + 3) * 300];
        }
    }

    // ---- LN stats over 300 (register + shuffle reduce) ----
    {
        float s1 = h0 + (has2 ? h1 : 0.f);
        float s2 = h0 * h0 + (has2 ? h1 * h1 : 0.f);
        for (int off = 32; off > 0; off >>= 1) {
            s1 += __shfl_down(s1, off);
            s2 += __shfl_down(s2, off);
        }
        int wv = tid >> 6, lane = tid & 63;
        if (lane == 0) { red[wv] = s1; red[4 + wv] = s2; }
    }
    __syncthreads();
    if (tid == 0) {
        float s1 = red[0] + red[1] + red[2] + red[3];
        float s2 = red[4] + red[5] + red[6] + red[7];
        float mean = s1 * (1.0f / 300.0f);
        float var = (s2 - 300.0f * mean * mean) * (1.0f / 299.0f);
        var = fmaxf(var, 0.0f);
        stats[0] = mean;
        stats[1] = 1.0f / (sqrtf(var) + 1e-6f);
    }
    __syncthreads();

    // ---- node = relu(LN(h)) -> global + srcL ----
    {
        float mean = stats[0], inv = stats[1];
        float n0 = fmaxf(lna[d0] * (h0 - mean) * inv + lnb[d0], 0.f);
        node_out[(size_t)row * 300 + d0] = n0;
        srcL[50 + d0] = n0;
        if (has2) {
            float n1 = fmaxf(lna[d1] * (h1 - mean) * inv + lnb[d1], 0.f);
            node_out[(size_t)row * 300 + d1] = n1;
            srcL[50 + d1] = n1;
        }
    }
    __syncthreads();

    // ---- R1/R2: split-K x5 over src=[diag|node] (Rw L2-resident, 150 KB) ----
    if (tid < 250) {
        int p = tid / 50, k = tid % 50;
        int srcOff, w1b, w2b, len;
        if (p == 0) { srcOff = 0;  w1b = 50 * 50;  w2b = 100 * 50; len = 50; }
        else {
            int dd = (p - 1) * 75;
            srcOff = 50 + dd; w1b = (150 + dd) * 50; w2b = (450 + dd) * 50; len = 75;
        }
        float r1 = 0.f, r2 = 0.f;
        const float* w1p = Rw + w1b + k;
        const float* w2p = Rw + w2b + k;
#pragma unroll 5
        for (int t = 0; t < len; ++t) {
            float sv = srcL[srcOff + t];
            r1 += sv * w1p[t * 50];
            r2 += sv * w2p[t * 50];
        }
        p1s[p][k] = r1; p2s[p][k] = r2;
    }
    __syncthreads();
    if (tid < 50) {
        float s1 = 0.f, s2 = rb[tid];
#pragma unroll
        for (int p = 0; p < 5; ++p) { s1 += p1s[p][tid]; s2 += p2s[p][tid]; }
        R1[(size_t)row * 50 + tid] = s1;
        R2[(size_t)row * 50 + tid] = s2;
    }
}

// ---------------- K2: edge_out = wa·Rw[0:50] (MFMA) + R1[j] + R2[i] ------------
__global__ void __launch_bounds__(256) k_edge(
    const float* __restrict__ wa,
    const float* __restrict__ Rw,
    const float* __restrict__ R1, const float* __restrict__ R2,
    float* __restrict__ eout)
{
    __shared__ __align__(16) unsigned char smem[27648];
    unsigned short* waA  = (unsigned short*)smem;            // 128*72 bf16
    unsigned short* rwBT = (unsigned short*)(smem + 18432);  // 64*72 bf16
    float* outF = (float*)smem;                              // alias: 6400 floats
    int tid = threadIdx.x;
    int bi = blockIdx.x;       // b*128 + i
    int b = bi >> 7;

    for (int idx = tid; idx < 2304; idx += 256) ((unsigned int*)rwBT)[idx] = 0u;
    for (int idx = tid; idx < 1408; idx += 256) {            // zero waA pad e in [50,72)
        int j = idx / 11, c = idx % 11;
        *((unsigned int*)(waA + j * 72 + 50) + c) = 0u;
    }
    __syncthreads();

    const float2* wap = (const float2*)(wa + (size_t)bi * 6400);
    for (int idx = tid; idx < 3200; idx += 256) {
        float2 v = wap[idx];
        int f = idx * 2;
        int j = f / 50, e = f % 50;
        unsigned int pack = (unsigned int)f2bf(v.x) | ((unsigned int)f2bf(v.y) << 16);
        *(unsigned int*)(waA + j * 72 + e) = pack;
    }
    for (int idx = tid; idx < 2500; idx += 256) {            // transpose+cvt Rw[0:50][0:50]
        int e = idx / 50, kk = idx % 50;
        rwBT[kk * 72 + e] = f2bf(Rw[idx]);
    }
    __syncthreads();

    int lane = tid & 63, wv = tid >> 6;
    int q = lane >> 4, lr = lane & 15;
    f32x4 acc[2][4] = {};

#pragma unroll
    for (int ks = 0; ks < 2; ++ks) {
        int e0 = ks * 32 + q * 8;
        bf16x8 a0 = *(const bf16x8*)&waA[(wv * 32 + lr) * 72 + e0];
        bf16x8 a1 = *(const bf16x8*)&waA[(wv * 32 + 16 + lr) * 72 + e0];
#pragma unroll
        for (int nt = 0; nt < 4; ++nt) {
            bf16x8 bb = *(const bf16x8*)&rwBT[(nt * 16 + lr) * 72 + e0];
            acc[0][nt] = __builtin_amdgcn_mfma_f32_16x16x32_bf16(a0, bb, acc[0][nt], 0, 0, 0);
            acc[1][nt] = __builtin_amdgcn_mfma_f32_16x16x32_bf16(a1, bb, acc[1][nt], 0, 0, 0);
        }
    }
    __syncthreads();   // staging LDS dead; alias as outF

    const float* r2p = R2 + (size_t)bi * 50;
#pragma unroll
    for (int nt = 0; nt < 4; ++nt) {
        int kk = nt * 16 + lr;
        if (kk < 50) {
            float r2v = r2p[kk];
#pragma unroll
            for (int mi = 0; mi < 2; ++mi) {
                int jbase = wv * 32 + mi * 16 + q * 4;
#pragma unroll
                for (int r = 0; r < 4; ++r)
                    outF[(jbase + r) * 50 + kk] = acc[mi][nt][r] + r2v;
            }
        }
    }
    __syncthreads();

    const float4* R1b = (const float4*)(R1 + (size_t)b * 6400);
    const float4* L4  = (const float4*)outF;
    float4* op4 = (float4*)(eout + (size_t)bi * 6400);
    for (int f4 = tid; f4 < 1600; f4 += 256) {
        float4 v = L4[f4];
        float4 r = R1b[f4];
        v.x += r.x; v.y += r.y; v.z += r.z; v.w += r.w;
        op4[f4] = v;
    }
}

extern "C" void kernel_launch(void* const* d_in, const int* in_sizes, int n_in,
                              void* d_out, int out_size, void* d_ws, size_t ws_size,
                              hipStream_t stream)
{
    const float* wps = (const float*)d_in[0];
    const float* wa  = (const float*)d_in[1];
    const float* x   = (const float*)d_in[2];
    // d_in[3] self_loop: identity on every channel, folded into msum (+1 on diag)
    const float* Ww  = (const float*)d_in[4];
    const float* Wb  = (const float*)d_in[5];
    const float* lna = (const float*)d_in[6];
    const float* lnb = (const float*)d_in[7];
    const float* Rw  = (const float*)d_in[8];
    const float* rb  = (const float*)d_in[9];

    float* R1 = (float*)d_ws;            // 51200 floats
    float* R2 = ((float*)d_ws) + 51200;  // 51200 floats

    float* node_out = (float*)d_out;             // 307200 floats
    float* edge_out = node_out + 307200;         // 6553600 floats

    k_node<<<1024, 256, 0, stream>>>(wps, wa, x, Ww, Wb, lna, lnb, Rw, rb,
                                     node_out, R1, R2);
    k_edge<<<1024, 256, 0, stream>>>(wa, Rw, R1, R2, edge_out);
}